// Round 1
// baseline (300.406 us; speedup 1.0000x reference)
//
#include <hip/hip_runtime.h>
#include <hip/hip_bf16.h>
#include <cstdint>

#define NCLOUDS 16
#define N_PER   2048
#define KNN_K   16

// ---------------------------------------------------------------------------
// KNN: grid = 16 clouds * 32 query-blocks; block = 256 threads.
// Thread (q, chunk): q in [0,64) within block, chunk in [0,4). Each thread
// scans 512 candidates from LDS keeping sorted top-16 in registers
// (branch-free unrolled insert, strict < keeps lower index on ties).
// 4 partial lists per query merged via u64 keys (d2_bits<<32 | idx) in LDS.
// ---------------------------------------------------------------------------
__global__ __launch_bounds__(256) void knn_kernel(const float* __restrict__ pos,
                                                  int* __restrict__ knn_out)
{
    __shared__ float px[N_PER], py[N_PER], pz[N_PER];
    __shared__ unsigned long long mk[256][KNN_K];

    const int cloud = blockIdx.x >> 5;   // 32 blocks per cloud
    const int qblk  = blockIdx.x & 31;
    const int tid   = threadIdx.x;

    const float* base = pos + (size_t)cloud * N_PER * 3;
    for (int t = tid; t < N_PER * 3; t += 256) {
        float v = base[t];
        int pt = t / 3;
        int d  = t - pt * 3;
        if (d == 0) px[pt] = v;
        else if (d == 1) py[pt] = v;
        else pz[pt] = v;
    }
    __syncthreads();

    const int q     = qblk * 64 + (tid & 63);
    const int chunk = tid >> 6;

    const float qx = px[q], qy = py[q], qz = pz[q];

    float kd[KNN_K];
    int   ki[KNN_K];
#pragma unroll
    for (int i = 0; i < KNN_K; ++i) { kd[i] = __builtin_inff(); ki[i] = 0; }

    const int j0 = chunk * (N_PER / 4);
#pragma unroll 1
    for (int jj = 0; jj < N_PER / 4; ++jj) {
        const int j = j0 + jj;
        // match reference association: (dx*dx + dy*dy) + dz*dz, no FMA contraction
        const float dx = __fsub_rn(qx, px[j]);
        const float dy = __fsub_rn(qy, py[j]);
        const float dz = __fsub_rn(qz, pz[j]);
        const float d2 = __fadd_rn(__fadd_rn(__fmul_rn(dx, dx), __fmul_rn(dy, dy)),
                                   __fmul_rn(dz, dz));
        bool lt[KNN_K];
#pragma unroll
        for (int i = 0; i < KNN_K; ++i) lt[i] = d2 < kd[i];
#pragma unroll
        for (int i = KNN_K - 1; i >= 1; --i) {
            kd[i] = lt[i] ? (lt[i - 1] ? kd[i - 1] : d2) : kd[i];
            ki[i] = lt[i] ? (lt[i - 1] ? ki[i - 1] : j)  : ki[i];
        }
        kd[0] = lt[0] ? d2 : kd[0];
        ki[0] = lt[0] ? j  : ki[0];
    }

#pragma unroll
    for (int r = 0; r < KNN_K; ++r)
        mk[tid][r] = ((unsigned long long)__float_as_uint(kd[r]) << 32) |
                     (unsigned int)ki[r];
    __syncthreads();

    if (tid < 64) {
        const int q2 = qblk * 64 + tid;
        int p0 = 0, p1 = 0, p2 = 0, p3 = 0;
        int* outp = knn_out + ((size_t)cloud * N_PER + q2) * KNN_K;
        for (int r = 0; r < KNN_K; ++r) {
            unsigned long long v0 = (p0 < KNN_K) ? mk[tid      ][p0] : ~0ULL;
            unsigned long long v1 = (p1 < KNN_K) ? mk[tid +  64][p1] : ~0ULL;
            unsigned long long v2 = (p2 < KNN_K) ? mk[tid + 128][p2] : ~0ULL;
            unsigned long long v3 = (p3 < KNN_K) ? mk[tid + 192][p3] : ~0ULL;
            unsigned long long mn01 = v0 < v1 ? v0 : v1;
            unsigned long long mn23 = v2 < v3 ? v2 : v3;
            unsigned long long mn   = mn01 < mn23 ? mn01 : mn23;
            if      (mn == v0) ++p0;
            else if (mn == v1) ++p1;
            else if (mn == v2) ++p2;
            else               ++p3;
            outp[r] = cloud * N_PER + (int)(unsigned int)(mn & 0xffffffffULL);
        }
    }
}

// ---------------------------------------------------------------------------
// Edge-MLP layer: lane = one edge (point p, neighbor slot k). hidden[32] and
// per-edge out in registers; weights are wave-uniform (scalar loads).
// Max over the 16 edge-lanes of each point via shfl_xor butterfly.
// CH = feature channels of h input (3 for layer1 where h = pos, 32 for layer2).
// ---------------------------------------------------------------------------
template <int CH>
__global__ __launch_bounds__(256) void layer_kernel(
    const float* __restrict__ pos,
    const float* __restrict__ hin,
    const int*   __restrict__ knn,
    const float* __restrict__ Wa, const float* __restrict__ ba,
    const float* __restrict__ Wb, const float* __restrict__ bb,
    float* __restrict__ hout)
{
    const int g = blockIdx.x * 256 + threadIdx.x;
    const int p = g >> 4;
    const int k = g & 15;
    const int j = knn[(size_t)p * KNN_K + k];

    float xh[CH];
#pragma unroll
    for (int c = 0; c < CH; ++c) xh[c] = hin[(size_t)j * CH + c];
    float sp[3];
#pragma unroll
    for (int d = 0; d < 3; ++d) sp[d] = pos[(size_t)j * 3 + d] - pos[(size_t)p * 3 + d];

    float hid[32];
#pragma unroll
    for (int c = 0; c < 32; ++c) {
        float s = ba[c];
#pragma unroll
        for (int d = 0; d < CH; ++d) s = fmaf(xh[d], Wa[d * 32 + c], s);
#pragma unroll
        for (int d = 0; d < 3; ++d)  s = fmaf(sp[d], Wa[(CH + d) * 32 + c], s);
        hid[c] = fmaxf(s, 0.0f);
    }

    float o0 = 0.0f, o1 = 0.0f;
#pragma unroll
    for (int c2 = 0; c2 < 32; ++c2) {
        float s = bb[c2];
#pragma unroll
        for (int c = 0; c < 32; ++c) s = fmaf(hid[c], Wb[c * 32 + c2], s);
        // max over 16 neighbor lanes (contiguous within the wave)
        s = fmaxf(s, __shfl_xor(s, 1));
        s = fmaxf(s, __shfl_xor(s, 2));
        s = fmaxf(s, __shfl_xor(s, 4));
        s = fmaxf(s, __shfl_xor(s, 8));
        if ((c2 & 15) == k) { if (c2 < 16) o0 = s; else o1 = s; }
    }
    // outer relu (reference: h = relu(layer(...)))
    hout[(size_t)p * 32 + k]      = fmaxf(o0, 0.0f);
    hout[(size_t)p * 32 + 16 + k] = fmaxf(o1, 0.0f);
}

// ---------------------------------------------------------------------------
// Global max pool over each cloud + linear classifier. 1 block per cloud.
// ---------------------------------------------------------------------------
__global__ __launch_bounds__(256) void pool_kernel(
    const float* __restrict__ h2, const float* __restrict__ Wc,
    const float* __restrict__ bc, float* __restrict__ out)
{
    __shared__ float red[8][32];
    __shared__ float sg[32];
    const int cloud = blockIdx.x;
    const int t = threadIdx.x;
    const int c = t & 31, row = t >> 5;
    float m = 0.0f;  // h2 >= 0 after relu
    for (int p = row; p < N_PER; p += 8)
        m = fmaxf(m, h2[((size_t)cloud * N_PER + p) * 32 + c]);
    red[row][c] = m;
    __syncthreads();
    if (t < 32) {
        float gv = red[0][t];
#pragma unroll
        for (int r = 1; r < 8; ++r) gv = fmaxf(gv, red[r][t]);
        sg[t] = gv;
    }
    __syncthreads();
    if (t < 10) {
        float s = bc[t];
#pragma unroll
        for (int c0 = 0; c0 < 32; ++c0) s = fmaf(sg[c0], Wc[c0 * 10 + t], s);
        out[cloud * 10 + t] = s;
    }
}

extern "C" void kernel_launch(void* const* d_in, const int* in_sizes, int n_in,
                              void* d_out, int out_size, void* d_ws, size_t ws_size,
                              hipStream_t stream)
{
    const float* pos = (const float*)d_in[0];
    // d_in[1] = batch (unused: graphs are sorted & equal-sized)
    const float* W1a = (const float*)d_in[2];
    const float* b1a = (const float*)d_in[3];
    const float* W1b = (const float*)d_in[4];
    const float* b1b = (const float*)d_in[5];
    const float* W2a = (const float*)d_in[6];
    const float* b2a = (const float*)d_in[7];
    const float* W2b = (const float*)d_in[8];
    const float* b2b = (const float*)d_in[9];
    const float* Wc  = (const float*)d_in[10];
    const float* bc  = (const float*)d_in[11];

    int*   knn = (int*)d_ws;                                  // 2 MB
    float* h1  = (float*)((char*)d_ws + (size_t)(2 << 20));   // 4 MB
    float* h2  = (float*)((char*)d_ws + (size_t)(6 << 20));   // 4 MB
    float* out = (float*)d_out;

    knn_kernel<<<dim3(NCLOUDS * 32), dim3(256), 0, stream>>>(pos, knn);
    layer_kernel<3><<<dim3((NCLOUDS * N_PER * KNN_K) / 256), dim3(256), 0, stream>>>(
        pos, pos, knn, W1a, b1a, W1b, b1b, h1);
    layer_kernel<32><<<dim3((NCLOUDS * N_PER * KNN_K) / 256), dim3(256), 0, stream>>>(
        pos, h1, knn, W2a, b2a, W2b, b2b, h2);
    pool_kernel<<<dim3(NCLOUDS), dim3(256), 0, stream>>>(h2, Wc, bc, out);
}

// Round 2
// 233.657 us; speedup vs baseline: 1.2857x; 1.2857x over previous
//
#include <hip/hip_runtime.h>
#include <hip/hip_bf16.h>
#include <cstdint>

#define NCLOUDS 16
#define N_PER   2048
#define KNN_K   16

// ---------------------------------------------------------------------------
// KNN v2: grid = 16 clouds * 64 query-blocks; block = 256 = 32 queries x 8
// chunks (q = tid&31, chunk = tid>>5; wave holds 2 chunks -> LDS pos reads
// are 2-address broadcasts, free). Pass 1 keeps the 16 smallest d2 per chunk
// with a min/max sorted insert (no index tracking). Lists staged in LDS
// ([r][chunk][q] layout: lane-consecutive, conflict-free), one lane per query
// pop-merges the 8 sorted lists to the exact global 16th-smallest d2. Pass 2
// rescans with the bit-identical d2 expression and emits indices d2<=thr via
// LDS-atomic slot allocation (order-free: downstream max-aggregates).
// ---------------------------------------------------------------------------
__global__ __launch_bounds__(256) void knn_kernel(const float* __restrict__ pos,
                                                  int* __restrict__ knn_out)
{
    __shared__ float px[N_PER], py[N_PER], pz[N_PER];
    __shared__ float kds[KNN_K][8][32];
    __shared__ float thr[32];
    __shared__ int   cnt[32];

    const int cloud = blockIdx.x >> 6;   // 64 blocks per cloud
    const int qblk  = blockIdx.x & 63;
    const int tid   = threadIdx.x;

    const float* base = pos + (size_t)cloud * N_PER * 3;
    for (int t = tid; t < N_PER * 3; t += 256) {
        float v = base[t];
        int pt = t / 3;
        int d  = t - pt * 3;
        if (d == 0) px[pt] = v;
        else if (d == 1) py[pt] = v;
        else pz[pt] = v;
    }
    __syncthreads();

    const int ql    = tid & 31;          // local query id
    const int chunk = tid >> 5;          // 8 chunks of 256 candidates
    const int q     = qblk * 32 + ql;

    const float qx = px[q], qy = py[q], qz = pz[q];

    float kd[KNN_K];
#pragma unroll
    for (int i = 0; i < KNN_K; ++i) kd[i] = __builtin_inff();

    const int j0 = chunk * (N_PER / 8);
#pragma unroll 4
    for (int jj = 0; jj < N_PER / 8; ++jj) {
        const int j = j0 + jj;
        // reference association: (dx*dx + dy*dy) + dz*dz, no FMA contraction
        const float dx = __fsub_rn(qx, px[j]);
        const float dy = __fsub_rn(qy, py[j]);
        const float dz = __fsub_rn(qz, pz[j]);
        const float d2 = __fadd_rn(__fadd_rn(__fmul_rn(dx, dx), __fmul_rn(dy, dy)),
                                   __fmul_rn(dz, dz));
        // sorted-ascending top-16 insert, values only: 2 ops/slot
#pragma unroll
        for (int i = KNN_K - 1; i >= 1; --i)
            kd[i] = fminf(kd[i], fmaxf(kd[i - 1], d2));
        kd[0] = fminf(kd[0], d2);
    }

#pragma unroll
    for (int r = 0; r < KNN_K; ++r)
        kds[r][chunk][ql] = kd[r];
    __syncthreads();

    if (tid < 32) {
        // pop-merge 8 sorted lists; 16th pop = global 16th-smallest d2
        float h0 = kds[0][0][tid], h1 = kds[0][1][tid], h2 = kds[0][2][tid],
              h3 = kds[0][3][tid], h4 = kds[0][4][tid], h5 = kds[0][5][tid],
              h6 = kds[0][6][tid], h7 = kds[0][7][tid];
        int p0 = 1, p1 = 1, p2 = 1, p3 = 1, p4 = 1, p5 = 1, p6 = 1, p7 = 1;
        float m = h0;
#pragma unroll 1
        for (int pop = 0; pop < KNN_K; ++pop) {
            const float m01 = fminf(h0, h1), m23 = fminf(h2, h3);
            const float m45 = fminf(h4, h5), m67 = fminf(h6, h7);
            m = fminf(fminf(m01, m23), fminf(m45, m67));
            bool done = false;
#define ADV(c)                                                                  \
            { bool a = !done && (h##c == m);                                    \
              if (a) { h##c = (p##c < KNN_K) ? kds[p##c][c][tid]                \
                                             : __builtin_inff();                \
                       ++p##c; done = true; } }
            ADV(0) ADV(1) ADV(2) ADV(3) ADV(4) ADV(5) ADV(6) ADV(7)
#undef ADV
        }
        thr[tid] = m;
        cnt[tid] = 0;
    }
    __syncthreads();

    const float T = thr[ql];
    int* outp = knn_out + ((size_t)cloud * N_PER + q) * KNN_K;
#pragma unroll 4
    for (int jj = 0; jj < N_PER / 8; ++jj) {
        const int j = j0 + jj;
        const float dx = __fsub_rn(qx, px[j]);
        const float dy = __fsub_rn(qy, py[j]);
        const float dz = __fsub_rn(qz, pz[j]);
        const float d2 = __fadd_rn(__fadd_rn(__fmul_rn(dx, dx), __fmul_rn(dy, dy)),
                                   __fmul_rn(dz, dz));
        if (d2 <= T) {
            int slot = atomicAdd(&cnt[ql], 1);
            if (slot < KNN_K) outp[slot] = cloud * N_PER + j;
        }
    }
}

// ---------------------------------------------------------------------------
// Edge-MLP layer: lane = one edge (point p, neighbor slot k). hidden[32] and
// per-edge out in registers; weights are wave-uniform (scalar loads).
// Max over the 16 edge-lanes of each point via shfl_xor butterfly.
// ---------------------------------------------------------------------------
template <int CH>
__global__ __launch_bounds__(256) void layer_kernel(
    const float* __restrict__ pos,
    const float* __restrict__ hin,
    const int*   __restrict__ knn,
    const float* __restrict__ Wa, const float* __restrict__ ba,
    const float* __restrict__ Wb, const float* __restrict__ bb,
    float* __restrict__ hout)
{
    const int g = blockIdx.x * 256 + threadIdx.x;
    const int p = g >> 4;
    const int k = g & 15;
    const int j = knn[(size_t)p * KNN_K + k];

    float xh[CH];
#pragma unroll
    for (int c = 0; c < CH; ++c) xh[c] = hin[(size_t)j * CH + c];
    float sp[3];
#pragma unroll
    for (int d = 0; d < 3; ++d) sp[d] = pos[(size_t)j * 3 + d] - pos[(size_t)p * 3 + d];

    float hid[32];
#pragma unroll
    for (int c = 0; c < 32; ++c) {
        float s = ba[c];
#pragma unroll
        for (int d = 0; d < CH; ++d) s = fmaf(xh[d], Wa[d * 32 + c], s);
#pragma unroll
        for (int d = 0; d < 3; ++d)  s = fmaf(sp[d], Wa[(CH + d) * 32 + c], s);
        hid[c] = fmaxf(s, 0.0f);
    }

    float o0 = 0.0f, o1 = 0.0f;
#pragma unroll
    for (int c2 = 0; c2 < 32; ++c2) {
        float s = bb[c2];
#pragma unroll
        for (int c = 0; c < 32; ++c) s = fmaf(hid[c], Wb[c * 32 + c2], s);
        s = fmaxf(s, __shfl_xor(s, 1));
        s = fmaxf(s, __shfl_xor(s, 2));
        s = fmaxf(s, __shfl_xor(s, 4));
        s = fmaxf(s, __shfl_xor(s, 8));
        if ((c2 & 15) == k) { if (c2 < 16) o0 = s; else o1 = s; }
    }
    hout[(size_t)p * 32 + k]      = fmaxf(o0, 0.0f);
    hout[(size_t)p * 32 + 16 + k] = fmaxf(o1, 0.0f);
}

// ---------------------------------------------------------------------------
// Global max pool over each cloud + linear classifier. 1 block per cloud.
// ---------------------------------------------------------------------------
__global__ __launch_bounds__(256) void pool_kernel(
    const float* __restrict__ h2, const float* __restrict__ Wc,
    const float* __restrict__ bc, float* __restrict__ out)
{
    __shared__ float red[8][32];
    __shared__ float sg[32];
    const int cloud = blockIdx.x;
    const int t = threadIdx.x;
    const int c = t & 31, row = t >> 5;
    float m = 0.0f;  // h2 >= 0 after relu
    for (int p = row; p < N_PER; p += 8)
        m = fmaxf(m, h2[((size_t)cloud * N_PER + p) * 32 + c]);
    red[row][c] = m;
    __syncthreads();
    if (t < 32) {
        float gv = red[0][t];
#pragma unroll
        for (int r = 1; r < 8; ++r) gv = fmaxf(gv, red[r][t]);
        sg[t] = gv;
    }
    __syncthreads();
    if (t < 10) {
        float s = bc[t];
#pragma unroll
        for (int c0 = 0; c0 < 32; ++c0) s = fmaf(sg[c0], Wc[c0 * 10 + t], s);
        out[cloud * 10 + t] = s;
    }
}

extern "C" void kernel_launch(void* const* d_in, const int* in_sizes, int n_in,
                              void* d_out, int out_size, void* d_ws, size_t ws_size,
                              hipStream_t stream)
{
    const float* pos = (const float*)d_in[0];
    const float* W1a = (const float*)d_in[2];
    const float* b1a = (const float*)d_in[3];
    const float* W1b = (const float*)d_in[4];
    const float* b1b = (const float*)d_in[5];
    const float* W2a = (const float*)d_in[6];
    const float* b2a = (const float*)d_in[7];
    const float* W2b = (const float*)d_in[8];
    const float* b2b = (const float*)d_in[9];
    const float* Wc  = (const float*)d_in[10];
    const float* bc  = (const float*)d_in[11];

    int*   knn = (int*)d_ws;                                  // 2 MB
    float* h1  = (float*)((char*)d_ws + (size_t)(2 << 20));   // 4 MB
    float* h2  = (float*)((char*)d_ws + (size_t)(6 << 20));   // 4 MB
    float* out = (float*)d_out;

    knn_kernel<<<dim3(NCLOUDS * 64), dim3(256), 0, stream>>>(pos, knn);
    layer_kernel<3><<<dim3((NCLOUDS * N_PER * KNN_K) / 256), dim3(256), 0, stream>>>(
        pos, pos, knn, W1a, b1a, W1b, b1b, h1);
    layer_kernel<32><<<dim3((NCLOUDS * N_PER * KNN_K) / 256), dim3(256), 0, stream>>>(
        pos, h1, knn, W2a, b2a, W2b, b2b, h2);
    pool_kernel<<<dim3(NCLOUDS), dim3(256), 0, stream>>>(h2, Wc, bc, out);
}

// Round 3
// 188.973 us; speedup vs baseline: 1.5897x; 1.2365x over previous
//
#include <hip/hip_runtime.h>
#include <hip/hip_bf16.h>
#include <cstdint>

#define NCLOUDS 16
#define N_PER   2048
#define KNN_K   16

#define QB    64   // queries per block
#define NCH   8    // candidate chunks (= waves per block)
#define CAND  (N_PER / NCH)
#define TOPC  6    // per-chunk top kept in pass 1
#define CAP   48   // pass-2 collection buffer per query

typedef unsigned long long u64;

__device__ __forceinline__ float dist2(float4 a, float4 b) {
    // reference association: (dx*dx + dy*dy) + dz*dz, no FMA contraction
    const float dx = __fsub_rn(a.x, b.x);
    const float dy = __fsub_rn(a.y, b.y);
    const float dz = __fsub_rn(a.z, b.z);
    return __fadd_rn(__fadd_rn(__fmul_rn(dx, dx), __fmul_rn(dy, dy)),
                     __fmul_rn(dz, dz));
}

// ---------------------------------------------------------------------------
// KNN v3: grid = 16 clouds * 32 qblocks (=512 = 2 blocks/CU, one full round).
// Block = 512 threads = 64 queries x 8 chunks; a wave = one chunk, so the
// candidate read pos4[j] is a full-wave LDS broadcast (ds_read_b128).
// Pass 1: top-6 d2 per chunk (11-op min/max insert, no indices).
// Merge: 16th smallest of the 48-value union = upper bound T-hat >= true T.
// Pass 2: collect all d2 <= T-hat as (d2,idx) u64 into per-query buffer.
// Select: per-chunk sorted-6 of buffer slices + 8-way pop-merge -> exact
// top-16 with reference tie order (d2 asc, idx asc).
// ---------------------------------------------------------------------------
__global__ __launch_bounds__(512) void knn_kernel(const float* __restrict__ pos,
                                                  int* __restrict__ knn_out)
{
    __shared__ float4 pos4[N_PER];         // 32 KB
    __shared__ float  kds[TOPC][NCH][QB];  // 12 KB
    __shared__ u64    buf[QB][CAP];        // 24 KB
    __shared__ float  thr[QB];
    __shared__ int    cnt[QB];

    const int cloud = blockIdx.x >> 5;     // 32 blocks per cloud
    const int qblk  = blockIdx.x & 31;
    const int tid   = threadIdx.x;

    const float* base = pos + (size_t)cloud * N_PER * 3;
    for (int pt = tid; pt < N_PER; pt += 512) {
        float x = base[3 * pt + 0];
        float y = base[3 * pt + 1];
        float z = base[3 * pt + 2];
        pos4[pt] = make_float4(x, y, z, 0.0f);
    }
    __syncthreads();

    const int ql    = tid & 63;            // local query id (lane id)
    const int chunk = tid >> 6;            // wave id
    const int q     = qblk * QB + ql;
    const int j0    = chunk * CAND;

    const float4 Q = pos4[q];

    // ---- pass 1: per-chunk top-6 distances ----
    float kd[TOPC];
#pragma unroll
    for (int i = 0; i < TOPC; ++i) kd[i] = __builtin_inff();

#pragma unroll 4
    for (int jj = 0; jj < CAND; ++jj) {
        const float d2 = dist2(Q, pos4[j0 + jj]);
#pragma unroll
        for (int i = TOPC - 1; i >= 1; --i)
            kd[i] = fminf(kd[i], fmaxf(kd[i - 1], d2));
        kd[0] = fminf(kd[0], d2);
    }
#pragma unroll
    for (int r = 0; r < TOPC; ++r)
        kds[r][chunk][ql] = kd[r];
    __syncthreads();

    // ---- merge: 16th smallest of the 48-value union -> threshold ----
    if (tid < QB) {
        float h0 = kds[0][0][tid], h1 = kds[0][1][tid], h2 = kds[0][2][tid],
              h3 = kds[0][3][tid], h4 = kds[0][4][tid], h5 = kds[0][5][tid],
              h6 = kds[0][6][tid], h7 = kds[0][7][tid];
        int p0 = 1, p1 = 1, p2 = 1, p3 = 1, p4 = 1, p5 = 1, p6 = 1, p7 = 1;
        float m = h0;
#pragma unroll 1
        for (int pop = 0; pop < KNN_K; ++pop) {
            const float m01 = fminf(h0, h1), m23 = fminf(h2, h3);
            const float m45 = fminf(h4, h5), m67 = fminf(h6, h7);
            m = fminf(fminf(m01, m23), fminf(m45, m67));
            bool done = false;
#define ADV(c)                                                                  \
            { bool a = !done && (h##c == m);                                    \
              if (a) { h##c = (p##c < TOPC) ? kds[p##c][c][tid]                 \
                                            : __builtin_inff();                 \
                       ++p##c; done = true; } }
            ADV(0) ADV(1) ADV(2) ADV(3) ADV(4) ADV(5) ADV(6) ADV(7)
#undef ADV
        }
        thr[tid] = m;
        cnt[tid] = 0;
    }
    __syncthreads();

    // ---- pass 2: collect all candidates with d2 <= T-hat ----
    const float T = thr[ql];
#pragma unroll 4
    for (int jj = 0; jj < CAND; ++jj) {
        const int j = j0 + jj;
        const float d2 = dist2(Q, pos4[j]);
        if (d2 <= T) {
            int slot = atomicAdd(&cnt[ql], 1);
            if (slot < CAP) buf[ql][slot] = ((u64)__float_as_uint(d2) << 32) |
                                            (unsigned int)j;
        }
    }
    __syncthreads();

    // ---- select stage A: each chunk-lane sorts its 6-slot slice ----
    {
        const int n = min(cnt[ql], CAP);
        u64 s[TOPC];
#pragma unroll
        for (int i = 0; i < TOPC; ++i) s[i] = ~0ULL;
#pragma unroll
        for (int t = 0; t < TOPC; ++t) {
            const int sl = chunk * TOPC + t;
            if (sl < n) {
                const u64 v = buf[ql][sl];
#pragma unroll
                for (int i = TOPC - 1; i >= 1; --i) {
                    const u64 hi = (s[i - 1] > v) ? s[i - 1] : v;
                    s[i] = (s[i] < hi) ? s[i] : hi;
                }
                s[0] = (s[0] < v) ? s[0] : v;
            }
        }
#pragma unroll
        for (int t = 0; t < TOPC; ++t)
            buf[ql][chunk * TOPC + t] = s[t];   // own slice: no cross-lane hazard
    }
    __syncthreads();

    // ---- select stage B: 8-way pop-merge of sorted-6 u64 lists -> top-16 ----
    if (tid < QB) {
        u64 v0 = buf[tid][0],  v1 = buf[tid][6],  v2 = buf[tid][12],
            v3 = buf[tid][18], v4 = buf[tid][24], v5 = buf[tid][30],
            v6 = buf[tid][36], v7 = buf[tid][42];
        int p0 = 1, p1 = 1, p2 = 1, p3 = 1, p4 = 1, p5 = 1, p6 = 1, p7 = 1;
        int* outp = knn_out + ((size_t)cloud * N_PER + qblk * QB + tid) * KNN_K;
#pragma unroll 1
        for (int r = 0; r < KNN_K; ++r) {
            u64 m01 = v0 < v1 ? v0 : v1, m23 = v2 < v3 ? v2 : v3;
            u64 m45 = v4 < v5 ? v4 : v5, m67 = v6 < v7 ? v6 : v7;
            u64 a = m01 < m23 ? m01 : m23, b = m45 < m67 ? m45 : m67;
            u64 m = a < b ? a : b;
            bool done = false;
#define ADV(c)                                                                  \
            { bool ad = !done && (v##c == m);                                   \
              if (ad) { v##c = (p##c < TOPC) ? buf[tid][c * TOPC + p##c]        \
                                             : ~0ULL;                           \
                        ++p##c; done = true; } }
            ADV(0) ADV(1) ADV(2) ADV(3) ADV(4) ADV(5) ADV(6) ADV(7)
#undef ADV
            outp[r] = cloud * N_PER + (int)(unsigned int)(m & 0xffffffffULL);
        }
    }
}

// ---------------------------------------------------------------------------
// Edge-MLP layer: lane = one edge (point p, neighbor slot k). hidden[32] and
// per-edge out in registers; weights are wave-uniform (scalar loads).
// Max over the 16 edge-lanes of each point via shfl_xor butterfly.
// ---------------------------------------------------------------------------
template <int CH>
__global__ __launch_bounds__(256) void layer_kernel(
    const float* __restrict__ pos,
    const float* __restrict__ hin,
    const int*   __restrict__ knn,
    const float* __restrict__ Wa, const float* __restrict__ ba,
    const float* __restrict__ Wb, const float* __restrict__ bb,
    float* __restrict__ hout)
{
    const int g = blockIdx.x * 256 + threadIdx.x;
    const int p = g >> 4;
    const int k = g & 15;
    const int j = knn[(size_t)p * KNN_K + k];

    float xh[CH];
    if constexpr (CH == 32) {
        const float4* hin4 = (const float4*)hin;   // rows are 128B-aligned
#pragma unroll
        for (int c4 = 0; c4 < 8; ++c4) {
            float4 t = hin4[(size_t)j * 8 + c4];
            xh[4 * c4 + 0] = t.x; xh[4 * c4 + 1] = t.y;
            xh[4 * c4 + 2] = t.z; xh[4 * c4 + 3] = t.w;
        }
    } else {
#pragma unroll
        for (int c = 0; c < CH; ++c) xh[c] = hin[(size_t)j * CH + c];
    }
    float sp[3];
#pragma unroll
    for (int d = 0; d < 3; ++d) sp[d] = pos[(size_t)j * 3 + d] - pos[(size_t)p * 3 + d];

    float hid[32];
#pragma unroll
    for (int c = 0; c < 32; ++c) {
        float s = ba[c];
#pragma unroll
        for (int d = 0; d < CH; ++d) s = fmaf(xh[d], Wa[d * 32 + c], s);
#pragma unroll
        for (int d = 0; d < 3; ++d)  s = fmaf(sp[d], Wa[(CH + d) * 32 + c], s);
        hid[c] = fmaxf(s, 0.0f);
    }

    float o0 = 0.0f, o1 = 0.0f;
#pragma unroll
    for (int c2 = 0; c2 < 32; ++c2) {
        float s = bb[c2];
#pragma unroll
        for (int c = 0; c < 32; ++c) s = fmaf(hid[c], Wb[c * 32 + c2], s);
        s = fmaxf(s, __shfl_xor(s, 1));
        s = fmaxf(s, __shfl_xor(s, 2));
        s = fmaxf(s, __shfl_xor(s, 4));
        s = fmaxf(s, __shfl_xor(s, 8));
        if ((c2 & 15) == k) { if (c2 < 16) o0 = s; else o1 = s; }
    }
    hout[(size_t)p * 32 + k]      = fmaxf(o0, 0.0f);
    hout[(size_t)p * 32 + 16 + k] = fmaxf(o1, 0.0f);
}

// ---------------------------------------------------------------------------
// Global max pool over each cloud + linear classifier. 1 block per cloud.
// ---------------------------------------------------------------------------
__global__ __launch_bounds__(256) void pool_kernel(
    const float* __restrict__ h2, const float* __restrict__ Wc,
    const float* __restrict__ bc, float* __restrict__ out)
{
    __shared__ float red[8][32];
    __shared__ float sg[32];
    const int cloud = blockIdx.x;
    const int t = threadIdx.x;
    const int c = t & 31, row = t >> 5;
    float m = 0.0f;  // h2 >= 0 after relu
    for (int p = row; p < N_PER; p += 8)
        m = fmaxf(m, h2[((size_t)cloud * N_PER + p) * 32 + c]);
    red[row][c] = m;
    __syncthreads();
    if (t < 32) {
        float gv = red[0][t];
#pragma unroll
        for (int r = 1; r < 8; ++r) gv = fmaxf(gv, red[r][t]);
        sg[t] = gv;
    }
    __syncthreads();
    if (t < 10) {
        float s = bc[t];
#pragma unroll
        for (int c0 = 0; c0 < 32; ++c0) s = fmaf(sg[c0], Wc[c0 * 10 + t], s);
        out[cloud * 10 + t] = s;
    }
}

extern "C" void kernel_launch(void* const* d_in, const int* in_sizes, int n_in,
                              void* d_out, int out_size, void* d_ws, size_t ws_size,
                              hipStream_t stream)
{
    const float* pos = (const float*)d_in[0];
    const float* W1a = (const float*)d_in[2];
    const float* b1a = (const float*)d_in[3];
    const float* W1b = (const float*)d_in[4];
    const float* b1b = (const float*)d_in[5];
    const float* W2a = (const float*)d_in[6];
    const float* b2a = (const float*)d_in[7];
    const float* W2b = (const float*)d_in[8];
    const float* b2b = (const float*)d_in[9];
    const float* Wc  = (const float*)d_in[10];
    const float* bc  = (const float*)d_in[11];

    int*   knn = (int*)d_ws;                                  // 2 MB
    float* h1  = (float*)((char*)d_ws + (size_t)(2 << 20));   // 4 MB
    float* h2  = (float*)((char*)d_ws + (size_t)(6 << 20));   // 4 MB
    float* out = (float*)d_out;

    knn_kernel<<<dim3(NCLOUDS * 32), dim3(512), 0, stream>>>(pos, knn);
    layer_kernel<3><<<dim3((NCLOUDS * N_PER * KNN_K) / 256), dim3(256), 0, stream>>>(
        pos, pos, knn, W1a, b1a, W1b, b1b, h1);
    layer_kernel<32><<<dim3((NCLOUDS * N_PER * KNN_K) / 256), dim3(256), 0, stream>>>(
        pos, h1, knn, W2a, b2a, W2b, b2b, h2);
    pool_kernel<<<dim3(NCLOUDS), dim3(256), 0, stream>>>(h2, Wc, bc, out);
}